// Round 1
// baseline (191.343 us; speedup 1.0000x reference)
//
#include <hip/hip_runtime.h>
#include <math.h>

#define NBATCH 32
#define AP     75600   // anchors per sample = 25200*27/9
#define NF     9       // 4 box + 1 obj + 4 cls
#define KTOP   300
#define NT     50
#define NC     4

__device__ __forceinline__ float sp_f(float x){           // jax.nn.softplus
    return fmaxf(x, 0.0f) + log1pf(expf(-fabsf(x)));
}
__device__ __forceinline__ float sig_f(float x){
    return 1.0f / (1.0f + expf(-x));
}
// monotone float->uint key (descending float order == descending uint order)
__device__ __forceinline__ unsigned fkey(float x){
    unsigned u = __float_as_uint(x);
    return (u & 0x80000000u) ? ~u : (u | 0x80000000u);
}
__device__ __forceinline__ float kinv(unsigned k){
    unsigned u = (k & 0x80000000u) ? (k & 0x7FFFFFFFu) : ~k;
    return __uint_as_float(u);
}
__device__ __forceinline__ unsigned load_key(const unsigned* k_s, const float* p_s, int i){
    return k_s ? k_s[i] : fkey(p_s[i*NF + 4]);
}

__global__ void build_keys_kernel(const float* __restrict__ pred, unsigned* __restrict__ keys){
    int s = blockIdx.y;
    int a = blockIdx.x * 256 + threadIdx.x;
    if (a < AP){
        float o = pred[(size_t)s * (AP*NF) + (size_t)a * NF + 4];
        keys[s * AP + a] = fkey(o);
    }
}

// find bin b (descending) with (#elems in bins>b) < need <= (#elems in bins>=b)
__device__ void find_bin(unsigned* hist, unsigned* ssup, int* sbin, unsigned* sabove,
                         unsigned need, int tid){
    if (tid < 32){
        unsigned a2 = 0;
        for (int i = 0; i < 64; ++i) a2 += hist[tid*64 + i];
        ssup[tid] = a2;
    }
    __syncthreads();
    if (tid == 0){
        unsigned a2 = 0; int g = 31;
        for (; g > 0; --g){ if (a2 + ssup[g] >= need) break; a2 += ssup[g]; }
        int b = g*64 + 63;
        for (;;){ unsigned h = hist[b]; if (a2 + h >= need || b == g*64) break; a2 += h; --b; }
        *sbin = b; *sabove = a2;
    }
    __syncthreads();
}

__global__ __launch_bounds__(1024) void loss_kernel(
    const float* __restrict__ pred,
    const unsigned* __restrict__ keysG,
    const float* __restrict__ tboxG,
    const int*   __restrict__ tclsG,
    float* __restrict__ out)
{
    const int s   = blockIdx.x;
    const int tid = threadIdx.x;
    const float*    p_s = pred + (size_t)s * (AP*NF);
    const unsigned* k_s = keysG ? (keysG + s * AP) : nullptr;

    __shared__ unsigned hist[2048];
    __shared__ unsigned ssup[32];
    __shared__ int sbin; __shared__ unsigned sabove;
    __shared__ double wsum[16];
    __shared__ double s_spsum;
    __shared__ unsigned tkKey[KTOP]; __shared__ int tkIdx[KTOP];
    __shared__ int eqIdx[2048];
    __shared__ int nGt, nEq;
    __shared__ int sIdx[KTOP];
    __shared__ float cand[KTOP][5];      // x1,y1,x2,y2,area
    __shared__ float tXY[NT][5];         // target xyxy + area
    __shared__ float tWH[NT][4];         // clipped xywh
    __shared__ int   tCl[NT];
    __shared__ int   chosenA[NT];
    __shared__ float corrJ[NT], clsJ[NT], boxJ[NT];
    __shared__ int   lastJ[NT];

    // ---- pass 1: level-1 histogram (top 11 bits) + softplus sum (double) ----
    for (int i = tid; i < 2048; i += 1024) hist[i] = 0;
    if (tid == 0){ nGt = 0; nEq = 0; }
    __syncthreads();
    double acc = 0.0;
    for (int i = tid; i < AP; i += 1024){
        unsigned ky = load_key(k_s, p_s, i);
        atomicAdd(&hist[ky >> 21], 1u);
        acc += (double)sp_f(kinv(ky));
    }
    for (int off = 32; off > 0; off >>= 1) acc += __shfl_down(acc, off);
    if ((tid & 63) == 0) wsum[tid >> 6] = acc;
    __syncthreads();
    if (tid == 0){
        double t = 0.0;
        for (int w = 0; w < 16; ++w) t += wsum[w];
        s_spsum = t;
    }
    __syncthreads();

    find_bin(hist, ssup, &sbin, &sabove, KTOP, tid);
    const int b1 = sbin; const unsigned above1 = sabove;
    const unsigned need2 = KTOP - above1;
    __syncthreads();

    // ---- pass 2: refine next 11 bits within bucket b1 ----
    for (int i = tid; i < 2048; i += 1024) hist[i] = 0;
    __syncthreads();
    for (int i = tid; i < AP; i += 1024){
        unsigned ky = load_key(k_s, p_s, i);
        if ((int)(ky >> 21) == b1) atomicAdd(&hist[(ky >> 10) & 0x7FFu], 1u);
    }
    __syncthreads();
    find_bin(hist, ssup, &sbin, &sabove, need2, tid);
    const int b2 = sbin; const unsigned above2 = sabove;
    const unsigned need3 = need2 - above2;
    const unsigned pref  = ((unsigned)b1 << 11) | (unsigned)b2;
    __syncthreads();

    // ---- pass 3: final 10 bits ----
    for (int i = tid; i < 2048; i += 1024) hist[i] = 0;
    __syncthreads();
    for (int i = tid; i < AP; i += 1024){
        unsigned ky = load_key(k_s, p_s, i);
        if ((ky >> 10) == pref) atomicAdd(&hist[ky & 0x3FFu], 1u);
    }
    __syncthreads();
    find_bin(hist, ssup, &sbin, &sabove, need3, tid);
    const int b3 = sbin; const unsigned above3 = sabove;
    const unsigned needEq = need3 - above3;
    const unsigned T      = ((unsigned)b1 << 21) | ((unsigned)b2 << 10) | (unsigned)b3;
    const unsigned cntGt  = above1 + above2 + above3;
    __syncthreads();

    // ---- collect: keys > T all in; keys == T take lowest-index ties ----
    for (int i = tid; i < AP; i += 1024){
        unsigned ky = load_key(k_s, p_s, i);
        if (ky > T){
            int p = atomicAdd(&nGt, 1);
            if (p < KTOP){ tkKey[p] = ky; tkIdx[p] = i; }
        } else if (ky == T){
            int p = atomicAdd(&nEq, 1);
            if (p < 2048) eqIdx[p] = i;
        }
    }
    __syncthreads();
    {
        int ne = min(nEq, 2048);
        for (int t = tid; t < ne; t += 1024){
            int mine = eqIdx[t]; int r = 0;
            for (int j = 0; j < ne; ++j) r += (eqIdx[j] < mine) ? 1 : 0;
            if ((unsigned)r < needEq){
                int p = (int)cntGt + r;
                if (p < KTOP){ tkKey[p] = T; tkIdx[p] = mine; }
            }
        }
    }
    __syncthreads();

    // ---- sort 300 by (key desc, idx asc) via rank (matches lax.top_k ties) ----
    if (tid < KTOP){
        unsigned myk = tkKey[tid]; int myi = tkIdx[tid];
        int r = 0;
        for (int j = 0; j < KTOP; ++j){
            unsigned kj = tkKey[j]; int ij = tkIdx[j];
            r += (kj > myk || (kj == myk && ij < myi)) ? 1 : 0;
        }
        sIdx[r] = myi;
    }
    __syncthreads();

    // ---- candidate boxes (sigmoid -> xyxy + area) ----
    if (tid < KTOP){
        int a = sIdx[tid];
        const float* row = p_s + a * NF;
        float bx = sig_f(row[0]), by = sig_f(row[1]);
        float bw = sig_f(row[2]), bh = sig_f(row[3]);
        float hw = bw * 0.5f, hh = bh * 0.5f;
        float x1 = bx - hw, y1 = by - hh, x2 = bx + hw, y2 = by + hh;
        cand[tid][0] = x1; cand[tid][1] = y1; cand[tid][2] = x2; cand[tid][3] = y2;
        cand[tid][4] = (x2 - x1) * (y2 - y1);
    }
    // ---- targets: clip, xyxy, area, class ----
    if (tid < NT){
        const float* tb = tboxG + ((size_t)s * NT + tid) * 4;
        float cx = fminf(fmaxf(tb[0], 0.f), 1.f);
        float cy = fminf(fmaxf(tb[1], 0.f), 1.f);
        float w  = fminf(fmaxf(tb[2], 0.f), 1.f);
        float h  = fminf(fmaxf(tb[3], 0.f), 1.f);
        tWH[tid][0] = cx; tWH[tid][1] = cy; tWH[tid][2] = w; tWH[tid][3] = h;
        float hw = w * 0.5f, hh = h * 0.5f;
        float x1 = cx - hw, y1 = cy - hh, x2 = cx + hw, y2 = cy + hh;
        tXY[tid][0] = x1; tXY[tid][1] = y1; tXY[tid][2] = x2; tXY[tid][3] = y2;
        tXY[tid][4] = (x2 - x1) * (y2 - y1);
        int c = tclsG[(size_t)s * NT + tid];
        tCl[tid] = min(max(c, 0), NC - 1);
    }
    __syncthreads();

    // ---- per-target argmax IoU over 300 candidates in top-k order (strict >) ----
    if (tid < NT){
        float tx1 = tXY[tid][0], ty1 = tXY[tid][1], tx2 = tXY[tid][2], ty2 = tXY[tid][3];
        float ta  = tXY[tid][4];
        float best = -1.0f; int bi = 0;
        for (int i = 0; i < KTOP; ++i){
            float iw = fminf(cand[i][2], tx2) - fmaxf(cand[i][0], tx1);
            iw = fmaxf(iw, 0.0f);
            float ih = fminf(cand[i][3], ty2) - fmaxf(cand[i][1], ty1);
            ih = fmaxf(ih, 0.0f);
            float inter = iw * ih;
            float uni = cand[i][4] + ta - inter;
            float iou = (uni > 0.0f) ? (inter / uni) : 0.0f;
            if (iou > best){ best = iou; bi = i; }
        }
        chosenA[tid] = sIdx[bi];
    }
    __syncthreads();

    // ---- per-target contributions; duplicates: last j wins rows, cls classes union ----
    if (tid < NT){
        int a = chosenA[tid];
        bool last = true;
        for (int j2 = tid + 1; j2 < NT; ++j2) if (chosenA[j2] == a) last = false;
        float corr = 0.f, clsv = 0.f, boxv = 0.f;
        if (last){
            const float* row = p_s + a * NF;
            float o = row[4];
            float spo = sp_f(o);
            corr = 2.0f * (spo - o) - 0.5f * spo;   // replace 0.5*sp with 2*(sp-x)
            unsigned mask = 0;
            for (int j2 = 0; j2 < NT; ++j2)
                if (chosenA[j2] == a) mask |= (1u << tCl[j2]);
            const float smooth_neg = (float)(0.05 / 3.0);
            for (int c = 0; c < NC; ++c){
                float x = row[5 + c];
                float t = ((mask >> c) & 1u) ? 0.95f : smooth_neg;
                clsv += sp_f(x) - x * t;
            }
            for (int c = 0; c < 4; ++c){
                float p = sig_f(row[c]);
                float d = fabsf(p - tWH[tid][c]);
                boxv += (d < 0.1f) ? (0.5f * d * d / 0.1f) : (d - 0.05f);
            }
        }
        lastJ[tid] = last ? 1 : 0;
        corrJ[tid] = corr; clsJ[tid] = clsv; boxJ[tid] = boxv;
    }
    __syncthreads();

    if (tid == 0){
        double corrS = 0, clsS = 0, boxS = 0; int np = 0;
        for (int j = 0; j < NT; ++j){
            if (lastJ[j]){ np++; corrS += corrJ[j]; clsS += clsJ[j]; boxS += boxJ[j]; }
        }
        float obj_l = (float)((0.5 * s_spsum + corrS) / (double)AP);
        float cls_l = (np > 0) ? (float)(clsS / ((double)np * NC)) : 0.f;
        float box_l = (np > 0) ? (float)(boxS / ((double)np * 4) * 2.0) : 0.f;
        atomicAdd(&out[1], box_l);
        atomicAdd(&out[2], cls_l);
        atomicAdd(&out[3], obj_l);
        atomicAdd(&out[0], box_l + cls_l + obj_l);
    }
}

extern "C" void kernel_launch(void* const* d_in, const int* in_sizes, int n_in,
                              void* d_out, int out_size, void* d_ws, size_t ws_size,
                              hipStream_t stream) {
    const float* pred = (const float*)d_in[0];
    const float* tbox = (const float*)d_in[1];
    const int*   tcls = (const int*)d_in[2];
    float* out = (float*)d_out;

    hipMemsetAsync(d_out, 0, (size_t)out_size * sizeof(float), stream);

    const size_t keysBytes = (size_t)NBATCH * AP * sizeof(unsigned);
    unsigned* keys = (ws_size >= keysBytes) ? (unsigned*)d_ws : nullptr;
    if (keys){
        dim3 grid((AP + 255) / 256, NBATCH);
        build_keys_kernel<<<grid, 256, 0, stream>>>(pred, keys);
    }
    loss_kernel<<<NBATCH, 1024, 0, stream>>>(pred, keys, tbox, tcls, out);
}

// Round 2
// 164.715 us; speedup vs baseline: 1.1617x; 1.1617x over previous
//
#include <hip/hip_runtime.h>
#include <math.h>

#define NBATCH 32
#define AP     75600   // anchors per sample = 25200*27/9
#define NF     9       // 4 box + 1 obj + 4 cls
#define KTOP   300
#define NT     50
#define NC     4
#define NBLK1  40      // wide blocks per sample
#define CCAP   4096    // candidate capacity per sample

__device__ __forceinline__ float sp_f(float x){           // jax.nn.softplus
    return fmaxf(x, 0.0f) + log1pf(expf(-fabsf(x)));
}
__device__ __forceinline__ float sig_f(float x){
    return 1.0f / (1.0f + expf(-x));
}
// monotone float->uint key (descending float order == descending uint order)
__device__ __forceinline__ unsigned fkey(float x){
    unsigned u = __float_as_uint(x);
    return (u & 0x80000000u) ? ~u : (u | 0x80000000u);
}
__device__ __forceinline__ float kinv(unsigned k){
    unsigned u = (k & 0x80000000u) ? (k & 0x7FFFFFFFu) : ~k;
    return __uint_as_float(u);
}

// ============================ FAST PATH =====================================

// K1: keys + softplus partial sums + level-1 histogram (top 11 bits)
__global__ __launch_bounds__(256) void k1_keys_hist(
    const float* __restrict__ pred, unsigned* __restrict__ keys,
    unsigned* __restrict__ hist, double* __restrict__ partials)
{
    const int s   = blockIdx.y;
    const int blk = blockIdx.x;
    const int tid = threadIdx.x;
    __shared__ unsigned lh[2048];
    __shared__ double wsum[4];
    for (int i = tid; i < 2048; i += 256) lh[i] = 0;
    __syncthreads();

    const float* p_s = pred + (size_t)s * (AP*NF);
    unsigned*    k_s = keys + (size_t)s * AP;
    double acc = 0.0;
    for (int i = blk*256 + tid; i < AP; i += NBLK1*256){
        float o = p_s[(size_t)i*NF + 4];
        unsigned ky = fkey(o);
        k_s[i] = ky;
        atomicAdd(&lh[ky >> 21], 1u);
        acc += (double)sp_f(o);
    }
    for (int off = 32; off > 0; off >>= 1) acc += __shfl_down(acc, off);
    if ((tid & 63) == 0) wsum[tid >> 6] = acc;
    __syncthreads();
    if (tid == 0) partials[s*NBLK1 + blk] = wsum[0] + wsum[1] + wsum[2] + wsum[3];

    unsigned* gh = hist + s * 2048;
    for (int i = tid; i < 2048; i += 256){
        unsigned v = lh[i];
        if (v) atomicAdd(&gh[i], v);
    }
}

// K2: per-sample threshold bin b1: count(bins > b1) < 300 <= count(bins >= b1)
__global__ __launch_bounds__(256) void k2_threshold(
    const unsigned* __restrict__ hist, unsigned* __restrict__ b1s)
{
    const int s = blockIdx.x;
    const int tid = threadIdx.x;
    const unsigned* gh = hist + s * 2048;
    __shared__ unsigned gs[256];
    unsigned a = 0;
    for (int i = 0; i < 8; ++i) a += gh[tid*8 + i];
    gs[tid] = a;
    __syncthreads();
    if (tid == 0){
        unsigned a2 = 0; int g = 255;
        for (; g > 0; --g){ if (a2 + gs[g] >= KTOP) break; a2 += gs[g]; }
        int b = g*8 + 7;
        for (;;){ unsigned h = gh[b]; if (a2 + h >= KTOP || b == g*8) break; a2 += h; --b; }
        b1s[s] = (unsigned)b;
    }
}

// K3: compact candidates with key >= (b1 << 21)
__global__ __launch_bounds__(256) void k3_compact(
    const unsigned* __restrict__ keys, const unsigned* __restrict__ b1s,
    unsigned* __restrict__ candKey, int* __restrict__ candIdx, int* __restrict__ candCnt)
{
    const int s = blockIdx.y;
    const unsigned thr = b1s[s] << 21;
    const unsigned* k_s = keys + (size_t)s * AP;
    for (int i = blockIdx.x*256 + threadIdx.x; i < AP; i += NBLK1*256){
        unsigned ky = k_s[i];
        if (ky >= thr){
            int p = atomicAdd(&candCnt[s], 1);
            if (p < CCAP){ candKey[s*CCAP + p] = ky; candIdx[s*CCAP + p] = i; }
        }
    }
}

// K4: exact rank-select top-300 among candidates, then IoU matching + losses
__global__ __launch_bounds__(1024) void k4_finish(
    const float* __restrict__ pred,
    const float* __restrict__ tboxG,
    const int*   __restrict__ tclsG,
    const unsigned* __restrict__ candKeyG, const int* __restrict__ candIdxG,
    const int* __restrict__ candCnt, const double* __restrict__ partials,
    float* __restrict__ out)
{
    const int s   = blockIdx.x;
    const int tid = threadIdx.x;
    const float* p_s = pred + (size_t)s * (AP*NF);

    __shared__ unsigned cKey[CCAP];
    __shared__ int      cIdx[CCAP];
    __shared__ int      sIdx[KTOP];
    __shared__ float    cand[KTOP][5];
    __shared__ float    tXY[NT][5];
    __shared__ float    tWH[NT][4];
    __shared__ int      tCl[NT];
    __shared__ int      chosenA[NT];
    __shared__ float    corrJ[NT], clsJ[NT], boxJ[NT];
    __shared__ int      lastJ[NT];

    const int n = min(candCnt[s], CCAP);
    for (int i = tid; i < n; i += 1024){
        cKey[i] = candKeyG[s*CCAP + i];
        cIdx[i] = candIdxG[s*CCAP + i];
    }
    __syncthreads();

    // rank by (key desc, idx asc) — matches lax.top_k stable tie semantics
    for (int i = tid; i < n; i += 1024){
        unsigned ki = cKey[i]; int ii = cIdx[i];
        int r = 0;
        for (int j = 0; j < n; ++j){
            unsigned kj = cKey[j]; int ij = cIdx[j];
            r += (kj > ki || (kj == ki && ij < ii)) ? 1 : 0;
        }
        if (r < KTOP) sIdx[r] = ii;
    }
    __syncthreads();

    const int kEff = min(KTOP, n);   // == KTOP by construction

    // candidate boxes (sigmoid -> xyxy + area)
    if (tid < kEff){
        int a = sIdx[tid];
        const float* row = p_s + (size_t)a * NF;
        float bx = sig_f(row[0]), by = sig_f(row[1]);
        float bw = sig_f(row[2]), bh = sig_f(row[3]);
        float hw = bw * 0.5f, hh = bh * 0.5f;
        float x1 = bx - hw, y1 = by - hh, x2 = bx + hw, y2 = by + hh;
        cand[tid][0] = x1; cand[tid][1] = y1; cand[tid][2] = x2; cand[tid][3] = y2;
        cand[tid][4] = (x2 - x1) * (y2 - y1);
    }
    // targets: clip, xyxy, area, class
    if (tid < NT){
        const float* tb = tboxG + ((size_t)s * NT + tid) * 4;
        float cx = fminf(fmaxf(tb[0], 0.f), 1.f);
        float cy = fminf(fmaxf(tb[1], 0.f), 1.f);
        float w  = fminf(fmaxf(tb[2], 0.f), 1.f);
        float h  = fminf(fmaxf(tb[3], 0.f), 1.f);
        tWH[tid][0] = cx; tWH[tid][1] = cy; tWH[tid][2] = w; tWH[tid][3] = h;
        float hw = w * 0.5f, hh = h * 0.5f;
        float x1 = cx - hw, y1 = cy - hh, x2 = cx + hw, y2 = cy + hh;
        tXY[tid][0] = x1; tXY[tid][1] = y1; tXY[tid][2] = x2; tXY[tid][3] = y2;
        tXY[tid][4] = (x2 - x1) * (y2 - y1);
        int c = tclsG[(size_t)s * NT + tid];
        tCl[tid] = min(max(c, 0), NC - 1);
    }
    __syncthreads();

    // per-target argmax IoU over candidates in top-k order (strict >)
    if (tid < NT){
        float tx1 = tXY[tid][0], ty1 = tXY[tid][1], tx2 = tXY[tid][2], ty2 = tXY[tid][3];
        float ta  = tXY[tid][4];
        float best = -1.0f; int bi = 0;
        for (int i = 0; i < kEff; ++i){
            float iw = fminf(cand[i][2], tx2) - fmaxf(cand[i][0], tx1);
            iw = fmaxf(iw, 0.0f);
            float ih = fminf(cand[i][3], ty2) - fmaxf(cand[i][1], ty1);
            ih = fmaxf(ih, 0.0f);
            float inter = iw * ih;
            float uni = cand[i][4] + ta - inter;
            float iou = (uni > 0.0f) ? (inter / uni) : 0.0f;
            if (iou > best){ best = iou; bi = i; }
        }
        chosenA[tid] = sIdx[bi];
    }
    __syncthreads();

    // per-target contributions; duplicates: last j wins rows, cls classes union
    if (tid < NT){
        int a = chosenA[tid];
        bool last = true;
        for (int j2 = tid + 1; j2 < NT; ++j2) if (chosenA[j2] == a) last = false;
        float corr = 0.f, clsv = 0.f, boxv = 0.f;
        if (last){
            const float* row = p_s + (size_t)a * NF;
            float o = row[4];
            float spo = sp_f(o);
            corr = 2.0f * (spo - o) - 0.5f * spo;   // replace 0.5*sp with 2*(sp-x)
            unsigned mask = 0;
            for (int j2 = 0; j2 < NT; ++j2)
                if (chosenA[j2] == a) mask |= (1u << tCl[j2]);
            const float smooth_neg = (float)(0.05 / 3.0);
            for (int c = 0; c < NC; ++c){
                float x = row[5 + c];
                float t = ((mask >> c) & 1u) ? 0.95f : smooth_neg;
                clsv += sp_f(x) - x * t;
            }
            for (int c = 0; c < 4; ++c){
                float p = sig_f(row[c]);
                float d = fabsf(p - tWH[tid][c]);
                boxv += (d < 0.1f) ? (0.5f * d * d / 0.1f) : (d - 0.05f);
            }
        }
        lastJ[tid] = last ? 1 : 0;
        corrJ[tid] = corr; clsJ[tid] = clsv; boxJ[tid] = boxv;
    }
    __syncthreads();

    if (tid == 0){
        double spsum = 0.0;
        for (int b = 0; b < NBLK1; ++b) spsum += partials[s*NBLK1 + b];
        double corrS = 0, clsS = 0, boxS = 0; int np = 0;
        for (int j = 0; j < NT; ++j){
            if (lastJ[j]){ np++; corrS += corrJ[j]; clsS += clsJ[j]; boxS += boxJ[j]; }
        }
        float obj_l = (float)((0.5 * spsum + corrS) / (double)AP);
        float cls_l = (np > 0) ? (float)(clsS / ((double)np * NC)) : 0.f;
        float box_l = (np > 0) ? (float)(boxS / ((double)np * 4) * 2.0) : 0.f;
        atomicAdd(&out[1], box_l);
        atomicAdd(&out[2], cls_l);
        atomicAdd(&out[3], obj_l);
        atomicAdd(&out[0], box_l + cls_l + obj_l);
    }
}

// ============================ FALLBACK (round-1) ============================

__device__ __forceinline__ unsigned load_key(const unsigned* k_s, const float* p_s, int i){
    return k_s ? k_s[i] : fkey(p_s[i*NF + 4]);
}

__global__ void build_keys_kernel(const float* __restrict__ pred, unsigned* __restrict__ keys){
    int s = blockIdx.y;
    int a = blockIdx.x * 256 + threadIdx.x;
    if (a < AP){
        float o = pred[(size_t)s * (AP*NF) + (size_t)a * NF + 4];
        keys[s * AP + a] = fkey(o);
    }
}

__device__ void find_bin(unsigned* hist, unsigned* ssup, int* sbin, unsigned* sabove,
                         unsigned need, int tid){
    if (tid < 32){
        unsigned a2 = 0;
        for (int i = 0; i < 64; ++i) a2 += hist[tid*64 + i];
        ssup[tid] = a2;
    }
    __syncthreads();
    if (tid == 0){
        unsigned a2 = 0; int g = 31;
        for (; g > 0; --g){ if (a2 + ssup[g] >= need) break; a2 += ssup[g]; }
        int b = g*64 + 63;
        for (;;){ unsigned h = hist[b]; if (a2 + h >= need || b == g*64) break; a2 += h; --b; }
        *sbin = b; *sabove = a2;
    }
    __syncthreads();
}

__global__ __launch_bounds__(1024) void loss_kernel_full(
    const float* __restrict__ pred,
    const unsigned* __restrict__ keysG,
    const float* __restrict__ tboxG,
    const int*   __restrict__ tclsG,
    float* __restrict__ out)
{
    const int s   = blockIdx.x;
    const int tid = threadIdx.x;
    const float*    p_s = pred + (size_t)s * (AP*NF);
    const unsigned* k_s = keysG ? (keysG + s * AP) : nullptr;

    __shared__ unsigned hist[2048];
    __shared__ unsigned ssup[32];
    __shared__ int sbin; __shared__ unsigned sabove;
    __shared__ double wsum[16];
    __shared__ double s_spsum;
    __shared__ unsigned tkKey[KTOP]; __shared__ int tkIdx[KTOP];
    __shared__ int eqIdx[2048];
    __shared__ int nGt, nEq;
    __shared__ int sIdx[KTOP];
    __shared__ float cand[KTOP][5];
    __shared__ float tXY[NT][5];
    __shared__ float tWH[NT][4];
    __shared__ int   tCl[NT];
    __shared__ int   chosenA[NT];
    __shared__ float corrJ[NT], clsJ[NT], boxJ[NT];
    __shared__ int   lastJ[NT];

    for (int i = tid; i < 2048; i += 1024) hist[i] = 0;
    if (tid == 0){ nGt = 0; nEq = 0; }
    __syncthreads();
    double acc = 0.0;
    for (int i = tid; i < AP; i += 1024){
        unsigned ky = load_key(k_s, p_s, i);
        atomicAdd(&hist[ky >> 21], 1u);
        acc += (double)sp_f(kinv(ky));
    }
    for (int off = 32; off > 0; off >>= 1) acc += __shfl_down(acc, off);
    if ((tid & 63) == 0) wsum[tid >> 6] = acc;
    __syncthreads();
    if (tid == 0){
        double t = 0.0;
        for (int w = 0; w < 16; ++w) t += wsum[w];
        s_spsum = t;
    }
    __syncthreads();

    find_bin(hist, ssup, &sbin, &sabove, KTOP, tid);
    const int b1 = sbin; const unsigned above1 = sabove;
    const unsigned need2 = KTOP - above1;
    __syncthreads();

    for (int i = tid; i < 2048; i += 1024) hist[i] = 0;
    __syncthreads();
    for (int i = tid; i < AP; i += 1024){
        unsigned ky = load_key(k_s, p_s, i);
        if ((int)(ky >> 21) == b1) atomicAdd(&hist[(ky >> 10) & 0x7FFu], 1u);
    }
    __syncthreads();
    find_bin(hist, ssup, &sbin, &sabove, need2, tid);
    const int b2 = sbin; const unsigned above2 = sabove;
    const unsigned need3 = need2 - above2;
    const unsigned pref  = ((unsigned)b1 << 11) | (unsigned)b2;
    __syncthreads();

    for (int i = tid; i < 2048; i += 1024) hist[i] = 0;
    __syncthreads();
    for (int i = tid; i < AP; i += 1024){
        unsigned ky = load_key(k_s, p_s, i);
        if ((ky >> 10) == pref) atomicAdd(&hist[ky & 0x3FFu], 1u);
    }
    __syncthreads();
    find_bin(hist, ssup, &sbin, &sabove, need3, tid);
    const int b3 = sbin; const unsigned above3 = sabove;
    const unsigned needEq = need3 - above3;
    const unsigned T      = ((unsigned)b1 << 21) | ((unsigned)b2 << 10) | (unsigned)b3;
    const unsigned cntGt  = above1 + above2 + above3;
    __syncthreads();

    for (int i = tid; i < AP; i += 1024){
        unsigned ky = load_key(k_s, p_s, i);
        if (ky > T){
            int p = atomicAdd(&nGt, 1);
            if (p < KTOP){ tkKey[p] = ky; tkIdx[p] = i; }
        } else if (ky == T){
            int p = atomicAdd(&nEq, 1);
            if (p < 2048) eqIdx[p] = i;
        }
    }
    __syncthreads();
    {
        int ne = min(nEq, 2048);
        for (int t = tid; t < ne; t += 1024){
            int mine = eqIdx[t]; int r = 0;
            for (int j = 0; j < ne; ++j) r += (eqIdx[j] < mine) ? 1 : 0;
            if ((unsigned)r < needEq){
                int p = (int)cntGt + r;
                if (p < KTOP){ tkKey[p] = T; tkIdx[p] = mine; }
            }
        }
    }
    __syncthreads();

    if (tid < KTOP){
        unsigned myk = tkKey[tid]; int myi = tkIdx[tid];
        int r = 0;
        for (int j = 0; j < KTOP; ++j){
            unsigned kj = tkKey[j]; int ij = tkIdx[j];
            r += (kj > myk || (kj == myk && ij < myi)) ? 1 : 0;
        }
        sIdx[r] = myi;
    }
    __syncthreads();

    if (tid < KTOP){
        int a = sIdx[tid];
        const float* row = p_s + a * NF;
        float bx = sig_f(row[0]), by = sig_f(row[1]);
        float bw = sig_f(row[2]), bh = sig_f(row[3]);
        float hw = bw * 0.5f, hh = bh * 0.5f;
        float x1 = bx - hw, y1 = by - hh, x2 = bx + hw, y2 = by + hh;
        cand[tid][0] = x1; cand[tid][1] = y1; cand[tid][2] = x2; cand[tid][3] = y2;
        cand[tid][4] = (x2 - x1) * (y2 - y1);
    }
    if (tid < NT){
        const float* tb = tboxG + ((size_t)s * NT + tid) * 4;
        float cx = fminf(fmaxf(tb[0], 0.f), 1.f);
        float cy = fminf(fmaxf(tb[1], 0.f), 1.f);
        float w  = fminf(fmaxf(tb[2], 0.f), 1.f);
        float h  = fminf(fmaxf(tb[3], 0.f), 1.f);
        tWH[tid][0] = cx; tWH[tid][1] = cy; tWH[tid][2] = w; tWH[tid][3] = h;
        float hw = w * 0.5f, hh = h * 0.5f;
        float x1 = cx - hw, y1 = cy - hh, x2 = cx + hw, y2 = cy + hh;
        tXY[tid][0] = x1; tXY[tid][1] = y1; tXY[tid][2] = x2; tXY[tid][3] = y2;
        tXY[tid][4] = (x2 - x1) * (y2 - y1);
        int c = tclsG[(size_t)s * NT + tid];
        tCl[tid] = min(max(c, 0), NC - 1);
    }
    __syncthreads();

    if (tid < NT){
        float tx1 = tXY[tid][0], ty1 = tXY[tid][1], tx2 = tXY[tid][2], ty2 = tXY[tid][3];
        float ta  = tXY[tid][4];
        float best = -1.0f; int bi = 0;
        for (int i = 0; i < KTOP; ++i){
            float iw = fminf(cand[i][2], tx2) - fmaxf(cand[i][0], tx1);
            iw = fmaxf(iw, 0.0f);
            float ih = fminf(cand[i][3], ty2) - fmaxf(cand[i][1], ty1);
            ih = fmaxf(ih, 0.0f);
            float inter = iw * ih;
            float uni = cand[i][4] + ta - inter;
            float iou = (uni > 0.0f) ? (inter / uni) : 0.0f;
            if (iou > best){ best = iou; bi = i; }
        }
        chosenA[tid] = sIdx[bi];
    }
    __syncthreads();

    if (tid < NT){
        int a = chosenA[tid];
        bool last = true;
        for (int j2 = tid + 1; j2 < NT; ++j2) if (chosenA[j2] == a) last = false;
        float corr = 0.f, clsv = 0.f, boxv = 0.f;
        if (last){
            const float* row = p_s + a * NF;
            float o = row[4];
            float spo = sp_f(o);
            corr = 2.0f * (spo - o) - 0.5f * spo;
            unsigned mask = 0;
            for (int j2 = 0; j2 < NT; ++j2)
                if (chosenA[j2] == a) mask |= (1u << tCl[j2]);
            const float smooth_neg = (float)(0.05 / 3.0);
            for (int c = 0; c < NC; ++c){
                float x = row[5 + c];
                float t = ((mask >> c) & 1u) ? 0.95f : smooth_neg;
                clsv += sp_f(x) - x * t;
            }
            for (int c = 0; c < 4; ++c){
                float p = sig_f(row[c]);
                float d = fabsf(p - tWH[tid][c]);
                boxv += (d < 0.1f) ? (0.5f * d * d / 0.1f) : (d - 0.05f);
            }
        }
        lastJ[tid] = last ? 1 : 0;
        corrJ[tid] = corr; clsJ[tid] = clsv; boxJ[tid] = boxv;
    }
    __syncthreads();

    if (tid == 0){
        double corrS = 0, clsS = 0, boxS = 0; int np = 0;
        for (int j = 0; j < NT; ++j){
            if (lastJ[j]){ np++; corrS += corrJ[j]; clsS += clsJ[j]; boxS += boxJ[j]; }
        }
        float obj_l = (float)((0.5 * s_spsum + corrS) / (double)AP);
        float cls_l = (np > 0) ? (float)(clsS / ((double)np * NC)) : 0.f;
        float box_l = (np > 0) ? (float)(boxS / ((double)np * 4) * 2.0) : 0.f;
        atomicAdd(&out[1], box_l);
        atomicAdd(&out[2], cls_l);
        atomicAdd(&out[3], obj_l);
        atomicAdd(&out[0], box_l + cls_l + obj_l);
    }
}

// ============================ LAUNCH ========================================

static inline size_t align256(size_t x){ return (x + 255) & ~(size_t)255; }

extern "C" void kernel_launch(void* const* d_in, const int* in_sizes, int n_in,
                              void* d_out, int out_size, void* d_ws, size_t ws_size,
                              hipStream_t stream) {
    const float* pred = (const float*)d_in[0];
    const float* tbox = (const float*)d_in[1];
    const int*   tcls = (const int*)d_in[2];
    float* out = (float*)d_out;

    hipMemsetAsync(d_out, 0, (size_t)out_size * sizeof(float), stream);

    // ws layout
    const size_t keysB  = (size_t)NBATCH * AP * sizeof(unsigned);
    const size_t oKeys  = 0;
    const size_t oHist  = align256(oKeys + keysB);
    const size_t oCnt   = oHist + (size_t)NBATCH * 2048 * sizeof(unsigned);  // contiguous w/ hist
    const size_t oB1    = align256(oCnt + NBATCH * sizeof(int));
    const size_t oPart  = align256(oB1 + NBATCH * sizeof(unsigned));
    const size_t oCKey  = align256(oPart + (size_t)NBATCH * NBLK1 * sizeof(double));
    const size_t oCIdx  = align256(oCKey + (size_t)NBATCH * CCAP * sizeof(unsigned));
    const size_t need   = oCIdx + (size_t)NBATCH * CCAP * sizeof(int);

    if (ws_size >= need){
        char* ws = (char*)d_ws;
        unsigned* keys    = (unsigned*)(ws + oKeys);
        unsigned* hist    = (unsigned*)(ws + oHist);
        int*      candCnt = (int*)     (ws + oCnt);
        unsigned* b1s     = (unsigned*)(ws + oB1);
        double*   parts   = (double*)  (ws + oPart);
        unsigned* candKey = (unsigned*)(ws + oCKey);
        int*      candIdx = (int*)     (ws + oCIdx);

        // zero hist + candCnt in one shot (contiguous)
        hipMemsetAsync(hist, 0, (size_t)NBATCH * 2048 * sizeof(unsigned) + NBATCH * sizeof(int), stream);

        dim3 gw(NBLK1, NBATCH);
        k1_keys_hist<<<gw, 256, 0, stream>>>(pred, keys, hist, parts);
        k2_threshold<<<NBATCH, 256, 0, stream>>>(hist, b1s);
        k3_compact<<<gw, 256, 0, stream>>>(keys, b1s, candKey, candIdx, candCnt);
        k4_finish<<<NBATCH, 1024, 0, stream>>>(pred, tbox, tcls, candKey, candIdx,
                                               candCnt, parts, out);
    } else {
        unsigned* keys = (ws_size >= keysB) ? (unsigned*)d_ws : nullptr;
        if (keys){
            dim3 grid((AP + 255) / 256, NBATCH);
            build_keys_kernel<<<grid, 256, 0, stream>>>(pred, keys);
        }
        loss_kernel_full<<<NBATCH, 1024, 0, stream>>>(pred, keys, tbox, tcls, out);
    }
}

// Round 3
// 97.284 us; speedup vs baseline: 1.9669x; 1.6931x over previous
//
#include <hip/hip_runtime.h>
#include <math.h>

#define NBATCH 32
#define AP     75600   // anchors per sample = 25200*27/9
#define NF     9       // 4 box + 1 obj + 4 cls
#define KTOP   300
#define NT     50
#define NC     4
#define NBLK1  40      // wide blocks per sample (k1)
#define NBLK3  16      // blocks per sample (k3) — short global-atomic chain
#define CCAP   4096    // candidate capacity per sample
#define BCAP   2048    // per-block LDS candidate buffer (expected ~30/block)

__device__ __forceinline__ float sp_f(float x){           // jax.nn.softplus
    return fmaxf(x, 0.0f) + log1pf(expf(-fabsf(x)));
}
__device__ __forceinline__ float sig_f(float x){
    return 1.0f / (1.0f + expf(-x));
}
// monotone float->uint key (descending float order == descending uint order)
__device__ __forceinline__ unsigned fkey(float x){
    unsigned u = __float_as_uint(x);
    return (u & 0x80000000u) ? ~u : (u | 0x80000000u);
}
__device__ __forceinline__ float kinv(unsigned k){
    unsigned u = (k & 0x80000000u) ? (k & 0x7FFFFFFFu) : ~k;
    return __uint_as_float(u);
}

// ============================ FAST PATH =====================================

// K1: keys + softplus partial sums + level-1 histogram (top 11 bits)
__global__ __launch_bounds__(256) void k1_keys_hist(
    const float* __restrict__ pred, unsigned* __restrict__ keys,
    unsigned* __restrict__ hist, double* __restrict__ partials)
{
    const int s   = blockIdx.y;
    const int blk = blockIdx.x;
    const int tid = threadIdx.x;
    __shared__ unsigned lh[2048];
    __shared__ double wsum[4];
    for (int i = tid; i < 2048; i += 256) lh[i] = 0;
    __syncthreads();

    const float* p_s = pred + (size_t)s * (AP*NF);
    unsigned*    k_s = keys + (size_t)s * AP;
    double acc = 0.0;
    for (int i = blk*256 + tid; i < AP; i += NBLK1*256){
        float o = p_s[(size_t)i*NF + 4];
        unsigned ky = fkey(o);
        k_s[i] = ky;
        atomicAdd(&lh[ky >> 21], 1u);
        acc += (double)sp_f(o);
    }
    for (int off = 32; off > 0; off >>= 1) acc += __shfl_down(acc, off);
    if ((tid & 63) == 0) wsum[tid >> 6] = acc;
    __syncthreads();
    if (tid == 0) partials[s*NBLK1 + blk] = wsum[0] + wsum[1] + wsum[2] + wsum[3];

    unsigned* gh = hist + s * 2048;
    for (int i = tid; i < 2048; i += 256){
        unsigned v = lh[i];
        if (v) atomicAdd(&gh[i], v);     // per-address chain depth = NBLK1, spread over 2048 addrs
    }
}

// K2: per-sample threshold bin b1: count(bins > b1) < 300 <= count(bins >= b1)
__global__ __launch_bounds__(256) void k2_threshold(
    const unsigned* __restrict__ hist, unsigned* __restrict__ b1s)
{
    const int s = blockIdx.x;
    const int tid = threadIdx.x;
    const unsigned* gh = hist + s * 2048;
    __shared__ unsigned gs[256];
    unsigned a = 0;
    for (int i = 0; i < 8; ++i) a += gh[tid*8 + i];
    gs[tid] = a;
    __syncthreads();
    if (tid == 0){
        unsigned a2 = 0; int g = 255;
        for (; g > 0; --g){ if (a2 + gs[g] >= KTOP) break; a2 += gs[g]; }
        int b = g*8 + 7;
        for (;;){ unsigned h = gh[b]; if (a2 + h >= KTOP || b == g*8) break; a2 += h; --b; }
        b1s[s] = (unsigned)b;
    }
}

// K3: compact candidates with key >= (b1 << 21).
// Block-local LDS buffering -> ONE global atomic per block (Guideline 12).
// Candidate order is irrelevant: k4 re-sorts exactly by (key desc, idx asc).
__global__ __launch_bounds__(256) void k3_compact(
    const unsigned* __restrict__ keys, const unsigned* __restrict__ b1s,
    unsigned* __restrict__ candKey, int* __restrict__ candIdx, int* __restrict__ candCnt)
{
    const int s = blockIdx.y;
    const unsigned thr = b1s[s] << 21;
    const unsigned* k_s = keys + (size_t)s * AP;

    __shared__ unsigned bKey[BCAP];
    __shared__ int      bIdx[BCAP];
    __shared__ int      lcnt;
    __shared__ int      gbase;
    if (threadIdx.x == 0) lcnt = 0;
    __syncthreads();

    for (int i = blockIdx.x*256 + threadIdx.x; i < AP; i += NBLK3*256){
        unsigned ky = k_s[i];
        if (ky >= thr){
            int p = atomicAdd(&lcnt, 1);          // LDS atomic, ~30 per block
            if (p < BCAP){ bKey[p] = ky; bIdx[p] = i; }
        }
    }
    __syncthreads();
    const int n = min(lcnt, BCAP);
    if (threadIdx.x == 0) gbase = (n > 0) ? atomicAdd(&candCnt[s], n) : 0;
    __syncthreads();
    for (int i = threadIdx.x; i < n; i += 256){
        int p = gbase + i;
        if (p < CCAP){ candKey[s*CCAP + p] = bKey[i]; candIdx[s*CCAP + p] = bIdx[i]; }
    }
}

// K4: exact rank-select top-300 among candidates, then IoU matching + losses
__global__ __launch_bounds__(1024) void k4_finish(
    const float* __restrict__ pred,
    const float* __restrict__ tboxG,
    const int*   __restrict__ tclsG,
    const unsigned* __restrict__ candKeyG, const int* __restrict__ candIdxG,
    const int* __restrict__ candCnt, const double* __restrict__ partials,
    float* __restrict__ out)
{
    const int s   = blockIdx.x;
    const int tid = threadIdx.x;
    const float* p_s = pred + (size_t)s * (AP*NF);

    __shared__ unsigned cKey[CCAP];
    __shared__ int      cIdx[CCAP];
    __shared__ int      sIdx[KTOP];
    __shared__ float    cand[KTOP][5];
    __shared__ float    tXY[NT][5];
    __shared__ float    tWH[NT][4];
    __shared__ int      tCl[NT];
    __shared__ int      chosenA[NT];
    __shared__ float    corrJ[NT], clsJ[NT], boxJ[NT];
    __shared__ int      lastJ[NT];

    const int n = min(candCnt[s], CCAP);
    for (int i = tid; i < n; i += 1024){
        cKey[i] = candKeyG[s*CCAP + i];
        cIdx[i] = candIdxG[s*CCAP + i];
    }
    __syncthreads();

    // rank by (key desc, idx asc) — matches lax.top_k stable tie semantics
    for (int i = tid; i < n; i += 1024){
        unsigned ki = cKey[i]; int ii = cIdx[i];
        int r = 0;
        for (int j = 0; j < n; ++j){
            unsigned kj = cKey[j]; int ij = cIdx[j];
            r += (kj > ki || (kj == ki && ij < ii)) ? 1 : 0;
        }
        if (r < KTOP) sIdx[r] = ii;
    }
    __syncthreads();

    const int kEff = min(KTOP, n);   // == KTOP by construction

    // candidate boxes (sigmoid -> xyxy + area)
    if (tid < kEff){
        int a = sIdx[tid];
        const float* row = p_s + (size_t)a * NF;
        float bx = sig_f(row[0]), by = sig_f(row[1]);
        float bw = sig_f(row[2]), bh = sig_f(row[3]);
        float hw = bw * 0.5f, hh = bh * 0.5f;
        float x1 = bx - hw, y1 = by - hh, x2 = bx + hw, y2 = by + hh;
        cand[tid][0] = x1; cand[tid][1] = y1; cand[tid][2] = x2; cand[tid][3] = y2;
        cand[tid][4] = (x2 - x1) * (y2 - y1);
    }
    // targets: clip, xyxy, area, class
    if (tid < NT){
        const float* tb = tboxG + ((size_t)s * NT + tid) * 4;
        float cx = fminf(fmaxf(tb[0], 0.f), 1.f);
        float cy = fminf(fmaxf(tb[1], 0.f), 1.f);
        float w  = fminf(fmaxf(tb[2], 0.f), 1.f);
        float h  = fminf(fmaxf(tb[3], 0.f), 1.f);
        tWH[tid][0] = cx; tWH[tid][1] = cy; tWH[tid][2] = w; tWH[tid][3] = h;
        float hw = w * 0.5f, hh = h * 0.5f;
        float x1 = cx - hw, y1 = cy - hh, x2 = cx + hw, y2 = cy + hh;
        tXY[tid][0] = x1; tXY[tid][1] = y1; tXY[tid][2] = x2; tXY[tid][3] = y2;
        tXY[tid][4] = (x2 - x1) * (y2 - y1);
        int c = tclsG[(size_t)s * NT + tid];
        tCl[tid] = min(max(c, 0), NC - 1);
    }
    __syncthreads();

    // per-target argmax IoU over candidates in top-k order (strict >)
    if (tid < NT){
        float tx1 = tXY[tid][0], ty1 = tXY[tid][1], tx2 = tXY[tid][2], ty2 = tXY[tid][3];
        float ta  = tXY[tid][4];
        float best = -1.0f; int bi = 0;
        for (int i = 0; i < kEff; ++i){
            float iw = fminf(cand[i][2], tx2) - fmaxf(cand[i][0], tx1);
            iw = fmaxf(iw, 0.0f);
            float ih = fminf(cand[i][3], ty2) - fmaxf(cand[i][1], ty1);
            ih = fmaxf(ih, 0.0f);
            float inter = iw * ih;
            float uni = cand[i][4] + ta - inter;
            float iou = (uni > 0.0f) ? (inter / uni) : 0.0f;
            if (iou > best){ best = iou; bi = i; }
        }
        chosenA[tid] = sIdx[bi];
    }
    __syncthreads();

    // per-target contributions; duplicates: last j wins rows, cls classes union
    if (tid < NT){
        int a = chosenA[tid];
        bool last = true;
        for (int j2 = tid + 1; j2 < NT; ++j2) if (chosenA[j2] == a) last = false;
        float corr = 0.f, clsv = 0.f, boxv = 0.f;
        if (last){
            const float* row = p_s + (size_t)a * NF;
            float o = row[4];
            float spo = sp_f(o);
            corr = 2.0f * (spo - o) - 0.5f * spo;   // replace 0.5*sp with 2*(sp-x)
            unsigned mask = 0;
            for (int j2 = 0; j2 < NT; ++j2)
                if (chosenA[j2] == a) mask |= (1u << tCl[j2]);
            const float smooth_neg = (float)(0.05 / 3.0);
            for (int c = 0; c < NC; ++c){
                float x = row[5 + c];
                float t = ((mask >> c) & 1u) ? 0.95f : smooth_neg;
                clsv += sp_f(x) - x * t;
            }
            for (int c = 0; c < 4; ++c){
                float p = sig_f(row[c]);
                float d = fabsf(p - tWH[tid][c]);
                boxv += (d < 0.1f) ? (0.5f * d * d / 0.1f) : (d - 0.05f);
            }
        }
        lastJ[tid] = last ? 1 : 0;
        corrJ[tid] = corr; clsJ[tid] = clsv; boxJ[tid] = boxv;
    }
    __syncthreads();

    if (tid == 0){
        double spsum = 0.0;
        for (int b = 0; b < NBLK1; ++b) spsum += partials[s*NBLK1 + b];
        double corrS = 0, clsS = 0, boxS = 0; int np = 0;
        for (int j = 0; j < NT; ++j){
            if (lastJ[j]){ np++; corrS += corrJ[j]; clsS += clsJ[j]; boxS += boxJ[j]; }
        }
        float obj_l = (float)((0.5 * spsum + corrS) / (double)AP);
        float cls_l = (np > 0) ? (float)(clsS / ((double)np * NC)) : 0.f;
        float box_l = (np > 0) ? (float)(boxS / ((double)np * 4) * 2.0) : 0.f;
        atomicAdd(&out[1], box_l);
        atomicAdd(&out[2], cls_l);
        atomicAdd(&out[3], obj_l);
        atomicAdd(&out[0], box_l + cls_l + obj_l);
    }
}

// ============================ FALLBACK (round-1) ============================

__device__ __forceinline__ unsigned load_key(const unsigned* k_s, const float* p_s, int i){
    return k_s ? k_s[i] : fkey(p_s[i*NF + 4]);
}

__global__ void build_keys_kernel(const float* __restrict__ pred, unsigned* __restrict__ keys){
    int s = blockIdx.y;
    int a = blockIdx.x * 256 + threadIdx.x;
    if (a < AP){
        float o = pred[(size_t)s * (AP*NF) + (size_t)a * NF + 4];
        keys[s * AP + a] = fkey(o);
    }
}

__device__ void find_bin(unsigned* hist, unsigned* ssup, int* sbin, unsigned* sabove,
                         unsigned need, int tid){
    if (tid < 32){
        unsigned a2 = 0;
        for (int i = 0; i < 64; ++i) a2 += hist[tid*64 + i];
        ssup[tid] = a2;
    }
    __syncthreads();
    if (tid == 0){
        unsigned a2 = 0; int g = 31;
        for (; g > 0; --g){ if (a2 + ssup[g] >= need) break; a2 += ssup[g]; }
        int b = g*64 + 63;
        for (;;){ unsigned h = hist[b]; if (a2 + h >= need || b == g*64) break; a2 += h; --b; }
        *sbin = b; *sabove = a2;
    }
    __syncthreads();
}

__global__ __launch_bounds__(1024) void loss_kernel_full(
    const float* __restrict__ pred,
    const unsigned* __restrict__ keysG,
    const float* __restrict__ tboxG,
    const int*   __restrict__ tclsG,
    float* __restrict__ out)
{
    const int s   = blockIdx.x;
    const int tid = threadIdx.x;
    const float*    p_s = pred + (size_t)s * (AP*NF);
    const unsigned* k_s = keysG ? (keysG + s * AP) : nullptr;

    __shared__ unsigned hist[2048];
    __shared__ unsigned ssup[32];
    __shared__ int sbin; __shared__ unsigned sabove;
    __shared__ double wsum[16];
    __shared__ double s_spsum;
    __shared__ unsigned tkKey[KTOP]; __shared__ int tkIdx[KTOP];
    __shared__ int eqIdx[2048];
    __shared__ int nGt, nEq;
    __shared__ int sIdx[KTOP];
    __shared__ float cand[KTOP][5];
    __shared__ float tXY[NT][5];
    __shared__ float tWH[NT][4];
    __shared__ int   tCl[NT];
    __shared__ int   chosenA[NT];
    __shared__ float corrJ[NT], clsJ[NT], boxJ[NT];
    __shared__ int   lastJ[NT];

    for (int i = tid; i < 2048; i += 1024) hist[i] = 0;
    if (tid == 0){ nGt = 0; nEq = 0; }
    __syncthreads();
    double acc = 0.0;
    for (int i = tid; i < AP; i += 1024){
        unsigned ky = load_key(k_s, p_s, i);
        atomicAdd(&hist[ky >> 21], 1u);
        acc += (double)sp_f(kinv(ky));
    }
    for (int off = 32; off > 0; off >>= 1) acc += __shfl_down(acc, off);
    if ((tid & 63) == 0) wsum[tid >> 6] = acc;
    __syncthreads();
    if (tid == 0){
        double t = 0.0;
        for (int w = 0; w < 16; ++w) t += wsum[w];
        s_spsum = t;
    }
    __syncthreads();

    find_bin(hist, ssup, &sbin, &sabove, KTOP, tid);
    const int b1 = sbin; const unsigned above1 = sabove;
    const unsigned need2 = KTOP - above1;
    __syncthreads();

    for (int i = tid; i < 2048; i += 1024) hist[i] = 0;
    __syncthreads();
    for (int i = tid; i < AP; i += 1024){
        unsigned ky = load_key(k_s, p_s, i);
        if ((int)(ky >> 21) == b1) atomicAdd(&hist[(ky >> 10) & 0x7FFu], 1u);
    }
    __syncthreads();
    find_bin(hist, ssup, &sbin, &sabove, need2, tid);
    const int b2 = sbin; const unsigned above2 = sabove;
    const unsigned need3 = need2 - above2;
    const unsigned pref  = ((unsigned)b1 << 11) | (unsigned)b2;
    __syncthreads();

    for (int i = tid; i < 2048; i += 1024) hist[i] = 0;
    __syncthreads();
    for (int i = tid; i < AP; i += 1024){
        unsigned ky = load_key(k_s, p_s, i);
        if ((ky >> 10) == pref) atomicAdd(&hist[ky & 0x3FFu], 1u);
    }
    __syncthreads();
    find_bin(hist, ssup, &sbin, &sabove, need3, tid);
    const int b3 = sbin; const unsigned above3 = sabove;
    const unsigned needEq = need3 - above3;
    const unsigned T      = ((unsigned)b1 << 21) | ((unsigned)b2 << 10) | (unsigned)b3;
    const unsigned cntGt  = above1 + above2 + above3;
    __syncthreads();

    for (int i = tid; i < AP; i += 1024){
        unsigned ky = load_key(k_s, p_s, i);
        if (ky > T){
            int p = atomicAdd(&nGt, 1);
            if (p < KTOP){ tkKey[p] = ky; tkIdx[p] = i; }
        } else if (ky == T){
            int p = atomicAdd(&nEq, 1);
            if (p < 2048) eqIdx[p] = i;
        }
    }
    __syncthreads();
    {
        int ne = min(nEq, 2048);
        for (int t = tid; t < ne; t += 1024){
            int mine = eqIdx[t]; int r = 0;
            for (int j = 0; j < ne; ++j) r += (eqIdx[j] < mine) ? 1 : 0;
            if ((unsigned)r < needEq){
                int p = (int)cntGt + r;
                if (p < KTOP){ tkKey[p] = T; tkIdx[p] = mine; }
            }
        }
    }
    __syncthreads();

    if (tid < KTOP){
        unsigned myk = tkKey[tid]; int myi = tkIdx[tid];
        int r = 0;
        for (int j = 0; j < KTOP; ++j){
            unsigned kj = tkKey[j]; int ij = tkIdx[j];
            r += (kj > myk || (kj == myk && ij < myi)) ? 1 : 0;
        }
        sIdx[r] = myi;
    }
    __syncthreads();

    if (tid < KTOP){
        int a = sIdx[tid];
        const float* row = p_s + a * NF;
        float bx = sig_f(row[0]), by = sig_f(row[1]);
        float bw = sig_f(row[2]), bh = sig_f(row[3]);
        float hw = bw * 0.5f, hh = bh * 0.5f;
        float x1 = bx - hw, y1 = by - hh, x2 = bx + hw, y2 = by + hh;
        cand[tid][0] = x1; cand[tid][1] = y1; cand[tid][2] = x2; cand[tid][3] = y2;
        cand[tid][4] = (x2 - x1) * (y2 - y1);
    }
    if (tid < NT){
        const float* tb = tboxG + ((size_t)s * NT + tid) * 4;
        float cx = fminf(fmaxf(tb[0], 0.f), 1.f);
        float cy = fminf(fmaxf(tb[1], 0.f), 1.f);
        float w  = fminf(fmaxf(tb[2], 0.f), 1.f);
        float h  = fminf(fmaxf(tb[3], 0.f), 1.f);
        tWH[tid][0] = cx; tWH[tid][1] = cy; tWH[tid][2] = w; tWH[tid][3] = h;
        float hw = w * 0.5f, hh = h * 0.5f;
        float x1 = cx - hw, y1 = cy - hh, x2 = cx + hw, y2 = cy + hh;
        tXY[tid][0] = x1; tXY[tid][1] = y1; tXY[tid][2] = x2; tXY[tid][3] = y2;
        tXY[tid][4] = (x2 - x1) * (y2 - y1);
        int c = tclsG[(size_t)s * NT + tid];
        tCl[tid] = min(max(c, 0), NC - 1);
    }
    __syncthreads();

    if (tid < NT){
        float tx1 = tXY[tid][0], ty1 = tXY[tid][1], tx2 = tXY[tid][2], ty2 = tXY[tid][3];
        float ta  = tXY[tid][4];
        float best = -1.0f; int bi = 0;
        for (int i = 0; i < KTOP; ++i){
            float iw = fminf(cand[i][2], tx2) - fmaxf(cand[i][0], tx1);
            iw = fmaxf(iw, 0.0f);
            float ih = fminf(cand[i][3], ty2) - fmaxf(cand[i][1], ty1);
            ih = fmaxf(ih, 0.0f);
            float inter = iw * ih;
            float uni = cand[i][4] + ta - inter;
            float iou = (uni > 0.0f) ? (inter / uni) : 0.0f;
            if (iou > best){ best = iou; bi = i; }
        }
        chosenA[tid] = sIdx[bi];
    }
    __syncthreads();

    if (tid < NT){
        int a = chosenA[tid];
        bool last = true;
        for (int j2 = tid + 1; j2 < NT; ++j2) if (chosenA[j2] == a) last = false;
        float corr = 0.f, clsv = 0.f, boxv = 0.f;
        if (last){
            const float* row = p_s + a * NF;
            float o = row[4];
            float spo = sp_f(o);
            corr = 2.0f * (spo - o) - 0.5f * spo;
            unsigned mask = 0;
            for (int j2 = 0; j2 < NT; ++j2)
                if (chosenA[j2] == a) mask |= (1u << tCl[j2]);
            const float smooth_neg = (float)(0.05 / 3.0);
            for (int c = 0; c < NC; ++c){
                float x = row[5 + c];
                float t = ((mask >> c) & 1u) ? 0.95f : smooth_neg;
                clsv += sp_f(x) - x * t;
            }
            for (int c = 0; c < 4; ++c){
                float p = sig_f(row[c]);
                float d = fabsf(p - tWH[tid][c]);
                boxv += (d < 0.1f) ? (0.5f * d * d / 0.1f) : (d - 0.05f);
            }
        }
        lastJ[tid] = last ? 1 : 0;
        corrJ[tid] = corr; clsJ[tid] = clsv; boxJ[tid] = boxv;
    }
    __syncthreads();

    if (tid == 0){
        double corrS = 0, clsS = 0, boxS = 0; int np = 0;
        for (int j = 0; j < NT; ++j){
            if (lastJ[j]){ np++; corrS += corrJ[j]; clsS += clsJ[j]; boxS += boxJ[j]; }
        }
        float obj_l = (float)((0.5 * s_spsum + corrS) / (double)AP);
        float cls_l = (np > 0) ? (float)(clsS / ((double)np * NC)) : 0.f;
        float box_l = (np > 0) ? (float)(boxS / ((double)np * 4) * 2.0) : 0.f;
        atomicAdd(&out[1], box_l);
        atomicAdd(&out[2], cls_l);
        atomicAdd(&out[3], obj_l);
        atomicAdd(&out[0], box_l + cls_l + obj_l);
    }
}

// ============================ LAUNCH ========================================

static inline size_t align256(size_t x){ return (x + 255) & ~(size_t)255; }

extern "C" void kernel_launch(void* const* d_in, const int* in_sizes, int n_in,
                              void* d_out, int out_size, void* d_ws, size_t ws_size,
                              hipStream_t stream) {
    const float* pred = (const float*)d_in[0];
    const float* tbox = (const float*)d_in[1];
    const int*   tcls = (const int*)d_in[2];
    float* out = (float*)d_out;

    hipMemsetAsync(d_out, 0, (size_t)out_size * sizeof(float), stream);

    // ws layout
    const size_t keysB  = (size_t)NBATCH * AP * sizeof(unsigned);
    const size_t oKeys  = 0;
    const size_t oHist  = align256(oKeys + keysB);
    const size_t oCnt   = oHist + (size_t)NBATCH * 2048 * sizeof(unsigned);  // contiguous w/ hist
    const size_t oB1    = align256(oCnt + NBATCH * sizeof(int));
    const size_t oPart  = align256(oB1 + NBATCH * sizeof(unsigned));
    const size_t oCKey  = align256(oPart + (size_t)NBATCH * NBLK1 * sizeof(double));
    const size_t oCIdx  = align256(oCKey + (size_t)NBATCH * CCAP * sizeof(unsigned));
    const size_t need   = oCIdx + (size_t)NBATCH * CCAP * sizeof(int);

    if (ws_size >= need){
        char* ws = (char*)d_ws;
        unsigned* keys    = (unsigned*)(ws + oKeys);
        unsigned* hist    = (unsigned*)(ws + oHist);
        int*      candCnt = (int*)     (ws + oCnt);
        unsigned* b1s     = (unsigned*)(ws + oB1);
        double*   parts   = (double*)  (ws + oPart);
        unsigned* candKey = (unsigned*)(ws + oCKey);
        int*      candIdx = (int*)     (ws + oCIdx);

        // zero hist + candCnt in one shot (contiguous)
        hipMemsetAsync(hist, 0, (size_t)NBATCH * 2048 * sizeof(unsigned) + NBATCH * sizeof(int), stream);

        dim3 gw1(NBLK1, NBATCH);
        dim3 gw3(NBLK3, NBATCH);
        k1_keys_hist<<<gw1, 256, 0, stream>>>(pred, keys, hist, parts);
        k2_threshold<<<NBATCH, 256, 0, stream>>>(hist, b1s);
        k3_compact<<<gw3, 256, 0, stream>>>(keys, b1s, candKey, candIdx, candCnt);
        k4_finish<<<NBATCH, 1024, 0, stream>>>(pred, tbox, tcls, candKey, candIdx,
                                               candCnt, parts, out);
    } else {
        unsigned* keys = (ws_size >= keysB) ? (unsigned*)d_ws : nullptr;
        if (keys){
            dim3 grid((AP + 255) / 256, NBATCH);
            build_keys_kernel<<<grid, 256, 0, stream>>>(pred, keys);
        }
        loss_kernel_full<<<NBATCH, 1024, 0, stream>>>(pred, keys, tbox, tcls, out);
    }
}